// Round 1
// baseline (110.908 us; speedup 1.0000x reference)
//
#include <hip/hip_runtime.h>
#include <hip/hip_bf16.h>

// RelationNetwork fused pipeline, bf16 MFMA (gfx950).
//
// Factorizations:
//  (1) pair@W1 = u[i]+v[j]  -> per-b 16x512x512 mini-GEMM (now fused into K2).
//  (2) ctx-ctx pair sum is choice-invariant -> computed once per b.
//  (3) f_phi fused (agg rows live in LDS).
//  (4) r9: K1 fused into K2. Each block computes its own UV[16][512] tile in
//      LDS (M=16, N=512, K=512; A = block's 16 X rows staged fp32->bf16 in
//      LDS; B = Wp streamed from L2 -- Wp fits each XCD's 4MB L2). Removes
//      the K1 launch, the 8.4 MB UV HBM round-trip, and K2's global staging
//      latency. h1 is built in ONE K=256 pass (no two-half split) since LDS
//      now holds the full 192x264 tile alongside UVs (118 KB total).
//
// ws layout (bytes):
//   [0,        524288)   Wp   bf16 [512][512]  Wp[j][k]=W1'[k][j]
//   [524288,   655360)   W2T  bf16 [256][256]
//   [655360,   786432)   W3T  bf16 [256][256]

typedef __bf16 bf16_t;
typedef bf16_t bf16x8 __attribute__((ext_vector_type(8)));
typedef bf16_t bf16x4 __attribute__((ext_vector_type(4)));
typedef float f32x4 __attribute__((ext_vector_type(4)));

#define MFMA16(a, b, c) __builtin_amdgcn_mfma_f32_16x16x32_bf16((a), (b), (c), 0, 0, 0)

// ---- K0: weight transposes via LDS tiles (96 blocks x 256 thr) -------------
// All sources have leading dim 256. Ts fp32 [64][65]: transpose-read bank
// stride 65%32=1 -> 2-way only. Reads 256 B coalesced, writes 128 B coalesced.
__global__ __launch_bounds__(256) void prep_kernel(
    const float* __restrict__ W1, const float* __restrict__ W2,
    const float* __restrict__ W3, bf16_t* __restrict__ Wp,
    bf16_t* __restrict__ W2T, bf16_t* __restrict__ W3T) {
  __shared__ float Ts[64][65];
  const int b = blockIdx.x;
  const int t = threadIdx.x;
  const int r = t >> 6;          // 0..3
  const int c = t & 63;
  const float* srcP;
  bf16_t* dstP;
  int srcRow, srcCol, dr0, dc0, dstride;
  if (b < 64) {                  // Wp tile: tk = b>>3, tj = b&7
    const int k0 = (b >> 3) * 64, j0 = (b & 7) * 64;
    srcP = W1; dstP = Wp; dstride = 512;
    srcRow = (j0 < 256) ? k0 : 512 + k0;
    srcCol = (j0 < 256) ? j0 : j0 - 256;
    dr0 = j0; dc0 = k0;
  } else if (b < 80) {           // W2T tile
    const int s = b - 64;
    const int k0 = (s >> 2) * 64, n0 = (s & 3) * 64;
    srcP = W2; dstP = W2T; dstride = 256;
    srcRow = k0; srcCol = n0; dr0 = n0; dc0 = k0;
  } else {                       // W3T tile
    const int s = b - 80;
    const int k0 = (s >> 2) * 64, n0 = (s & 3) * 64;
    srcP = W3; dstP = W3T; dstride = 256;
    srcRow = k0; srcCol = n0; dr0 = n0; dc0 = k0;
  }
  for (int i = 0; i < 16; ++i) {           // 16 iters x 4 rows = 64 rows
    const int a = i * 4 + r;
    Ts[a][c] = srcP[(size_t)(srcRow + a) * 256 + srcCol + c];
  }
  __syncthreads();
  for (int i = 0; i < 16; ++i) {
    const int j = i * 4 + r;
    dstP[(size_t)(dr0 + j) * dstride + dc0 + c] = (bf16_t)Ts[c][j];
  }
}

// ---- K2: fully fused per-b pipeline. One block per b (256 blk, 512 thr). --
// Phase 1: stage X[16][512] fp32->bf16 -> Xs; UV[16][512] = X @ Wp^T -> UVs.
// Phase 2: h1[192][256] = relu(u[i]+v[j]+b1) built from UVs (LDS only).
//   Rows r<56 ctx pair; 56..63 zero pad; r=64+ch*16+rr choice pair.
// Phase 3: h2 partial = h1 @ W2T (K=256 single pass). 8 waves: w&1 -> mt half
//   (6 tiles), w>>1 -> nt quarter.
// Epilogue (LDS overlay, h1 dead): S[9][256] column sums -> Ag[16][264] bf16
//   agg rows -> f_phi MFMA vs W3T -> W4 dot -> out[b*8+ch].
//
// LDS map (118016 B total):
//   [0,     16640)  UVs bf16 [16][520]   (520: stride 260dw % 32 = 4 -> <=4-way)
//   [16640, 118016) h1  bf16 [192][264]  (264: stride 132dw % 32 = 4 -> 2-way)
//     overlays: Xs bf16 [16][520] @16640 (phase-1 A-tile, dead after phase 1)
//               S f32 [9][256] @16640; Ag bf16 [16][264] @+9216; red @+17664
__global__ __launch_bounds__(512) void k2_kernel(
    const float* __restrict__ ctx, const float* __restrict__ cho,
    const bf16_t* __restrict__ Wp, const float* __restrict__ b1,
    const float* __restrict__ b2, const bf16_t* __restrict__ W2T,
    const bf16_t* __restrict__ W3T, const float* __restrict__ b3,
    const float* __restrict__ W4, const float* __restrict__ b4,
    float* __restrict__ out) {
  __shared__ char smem[118016];
  bf16_t (*UVs)[520] = (bf16_t(*)[520])smem;
  bf16_t (*Xs)[520]  = (bf16_t(*)[520])(smem + 16640);
  bf16_t (*h1)[264]  = (bf16_t(*)[264])(smem + 16640);
  float  (*S)[256]   = (float(*)[256])(smem + 16640);
  bf16_t (*Ag)[264]  = (bf16_t(*)[264])(smem + 16640 + 9216);
  float  (*red)[8]   = (float(*)[8])(smem + 16640 + 9216 + 8448);
  const int b = blockIdx.x;
  const int t = threadIdx.x;
  const int lane = t & 63;
  const int w = t >> 6;
  const int col = lane & 15;
  const int quad = lane >> 4;

  // ---- Phase 1a: stage X -> Xs (bf16). 32 thr/row, 16 floats each,
  // 64 B/lane coalesced reads; LDS writes bank-uniform. ----
  {
    const int row = t >> 5;          // 0..15
    const int c0 = (t & 31) * 16;
    const float* src = (row < 8) ? ctx + ((size_t)b * 8 + row) * 512
                                 : cho + ((size_t)b * 8 + (row - 8)) * 512;
    const f32x4 x0 = *(const f32x4*)(src + c0);
    const f32x4 x1 = *(const f32x4*)(src + c0 + 4);
    const f32x4 x2 = *(const f32x4*)(src + c0 + 8);
    const f32x4 x3 = *(const f32x4*)(src + c0 + 12);
    bf16x8 y0, y1;
    for (int e = 0; e < 4; ++e) { y0[e] = (bf16_t)x0[e]; y0[4 + e] = (bf16_t)x1[e]; }
    for (int e = 0; e < 4; ++e) { y1[e] = (bf16_t)x2[e]; y1[4 + e] = (bf16_t)x3[e]; }
    *(bf16x8*)(&Xs[row][c0]) = y0;
    *(bf16x8*)(&Xs[row][c0 + 8]) = y1;
  }
  __syncthreads();

  // ---- Phase 1b: UVs = X @ Wp^T (M=16, N=512, K=512). Wave w owns n in
  // [w*64, w*64+64): streams a contiguous 64-row slab of Wp from L2. ----
  {
    f32x4 acc1[4] = {};
    for (int ks = 0; ks < 16; ++ks) {
      const int k = ks * 32 + quad * 8;
      const bf16x8 af = *(const bf16x8*)(&Xs[col][k]);
      for (int nt = 0; nt < 4; ++nt) {
        const int n = w * 64 + nt * 16 + col;
        const bf16x8 bfr = *(const bf16x8*)(Wp + (size_t)n * 512 + k);
        acc1[nt] = MFMA16(af, bfr, acc1[nt]);
      }
    }
    for (int nt = 0; nt < 4; ++nt) {
      const int n = w * 64 + nt * 16 + col;
      for (int reg = 0; reg < 4; ++reg)
        UVs[quad * 4 + reg][n] = (bf16_t)acc1[nt][reg];
    }
  }
  __syncthreads();   // UVs ready; Xs dead -> h1 may overlay

  // ---- Phase 2: h1 = relu(u[i]+v[j]+b1), all LDS. 2 thr/row x 128 cols. ----
  if (t < 384) {
    const int sr = t >> 1;
    const int sc0 = (t & 1) * 128;
    const bf16_t* su = nullptr;
    const bf16_t* sv = nullptr;
    if (sr < 56) {
      const int i = sr / 7;
      const int jj = sr - i * 7;
      const int j = jj + (jj >= i ? 1 : 0);
      su = UVs[i];
      sv = UVs[j] + 256;
    } else if (sr >= 64) {
      const int ch = (sr - 64) >> 4;
      const int rr = (sr - 64) & 15;
      if (rr < 8) { su = UVs[8 + ch]; sv = UVs[rr] + 256; }
      else        { su = UVs[rr - 8]; sv = UVs[8 + ch] + 256; }
    }
    if (su) {
      for (int c = sc0; c < sc0 + 128; c += 8) {
        const bf16x8 u8 = *(const bf16x8*)(su + c);
        const bf16x8 v8 = *(const bf16x8*)(sv + c);
        const f32x4 bb0 = *(const f32x4*)(b1 + c);
        const f32x4 bb1 = *(const f32x4*)(b1 + c + 4);
        bf16x8 y;
        for (int e = 0; e < 4; ++e)
          y[e] = (bf16_t)fmaxf((float)u8[e] + (float)v8[e] + bb0[e], 0.0f);
        for (int e = 0; e < 4; ++e)
          y[4 + e] = (bf16_t)fmaxf((float)u8[4 + e] + (float)v8[4 + e] + bb1[e], 0.0f);
        *(bf16x8*)(&h1[sr][c]) = y;
      }
    } else {               // zero-pad rows 56..63
      for (int c = sc0; c < sc0 + 128; c += 8)
        *(bf16x8*)(&h1[sr][c]) = (bf16x8)0.0f;
    }
  }
  __syncthreads();

  // ---- Phase 3: h1 @ W2T, K=256 single pass. ----
  const int mtb = (w & 1) * 6;   // mt base (6 tiles)
  const int q = w >> 1;          // nt quarter
  f32x4 acc[6][4] = {};
  for (int ks = 0; ks < 8; ++ks) {
    const int k = ks * 32 + quad * 8;
    bf16x8 af[6], bfr[4];
    for (int mt = 0; mt < 6; ++mt)
      af[mt] = *(const bf16x8*)(&h1[(mtb + mt) * 16 + col][k]);
    for (int nt = 0; nt < 4; ++nt) {
      const int n = q * 64 + nt * 16 + col;
      bfr[nt] = *(const bf16x8*)(W2T + (size_t)n * 256 + k);
    }
    for (int mt = 0; mt < 6; ++mt)
      for (int nt = 0; nt < 4; ++nt)
        acc[mt][nt] = MFMA16(af[mt], bfr[nt], acc[mt][nt]);
  }
  __syncthreads();   // MFMAs done; h1 dead -> S/Ag/red may overlay

  // ---- Epilogue: tile-column sums of relu(acc + b2) -> S ----
  for (int nt = 0; nt < 4; ++nt) {
    const int n = q * 64 + nt * 16 + col;
    const float b2c = b2[n];
    float sctx = 0.0f;
    for (int mt = 0; mt < 6; ++mt) {
      const int gm = mtb + mt;
      float s = 0.0f;
      for (int reg = 0; reg < 4; ++reg) {
        const int row = gm * 16 + quad * 4 + reg;
        if (row < 56 || row >= 64) s += fmaxf(acc[mt][nt][reg] + b2c, 0.0f);
      }
      s += __shfl_xor(s, 16);
      s += __shfl_xor(s, 32);
      if (gm < 4) {
        sctx += s;                       // only waves with mtb==0
      } else if (lane < 16) {
        S[1 + (gm - 4)][n] = s;
      }
    }
    if (mtb == 0 && lane < 16) S[0][n] = sctx;
  }
  __syncthreads();
  // Ag rows 0..7 = bf16 agg for each choice; rows 8..15 zero (M=16 pad)
  {
    const int ch = t >> 6;
    const int n0 = (t & 63) * 4;
    bf16x4 y;
    for (int e = 0; e < 4; ++e)
      y[e] = (bf16_t)((S[0][n0 + e] + S[1 + ch][n0 + e]) * (1.0f / 72.0f));
    *(bf16x4*)(&Ag[ch][n0]) = y;
    *(bf16x4*)(&Ag[8 + ch][n0]) = (bf16x4)0.0f;
  }
  __syncthreads();
  // f_phi: g = relu(Ag@W3+b3); score = g@W4 + b4. wave w -> n in [w*32,+32).
  f32x4 acc2[2] = {};
  for (int ks = 0; ks < 8; ++ks) {
    const int k = ks * 32 + quad * 8;
    const bf16x8 af = *(const bf16x8*)(&Ag[col][k]);
    for (int nt = 0; nt < 2; ++nt) {
      const int n = w * 32 + nt * 16 + col;
      const bf16x8 bfr = *(const bf16x8*)(W3T + (size_t)n * 256 + k);
      acc2[nt] = MFMA16(af, bfr, acc2[nt]);
    }
  }
  for (int reg = 0; reg < 4; ++reg) {
    float pr = 0.0f;
    for (int nt = 0; nt < 2; ++nt) {
      const int n = w * 32 + nt * 16 + col;
      pr += fmaxf(acc2[nt][reg] + b3[n], 0.0f) * W4[n];
    }
    pr += __shfl_xor(pr, 1);
    pr += __shfl_xor(pr, 2);
    pr += __shfl_xor(pr, 4);
    pr += __shfl_xor(pr, 8);
    if (col == 0 && quad < 2) red[w][quad * 4 + reg] = pr;  // rows 8..15 dropped
  }
  __syncthreads();
  if (t < 8) {
    float sc = b4[0];
    for (int ww = 0; ww < 8; ++ww) sc += red[ww][t];
    out[b * 8 + t] = sc;
  }
}

extern "C" void kernel_launch(void* const* d_in, const int* in_sizes, int n_in,
                              void* d_out, int out_size, void* d_ws, size_t ws_size,
                              hipStream_t stream) {
  (void)in_sizes; (void)n_in; (void)out_size; (void)ws_size;
  const float* ctx = (const float*)d_in[0];
  const float* cho = (const float*)d_in[1];
  const float* W1  = (const float*)d_in[2];
  const float* b1  = (const float*)d_in[3];
  const float* W2  = (const float*)d_in[4];
  const float* b2  = (const float*)d_in[5];
  const float* W3  = (const float*)d_in[6];
  const float* b3  = (const float*)d_in[7];
  const float* W4  = (const float*)d_in[8];
  const float* b4  = (const float*)d_in[9];
  char* ws = (char*)d_ws;
  bf16_t* Wp   = (bf16_t*)(ws + 0);
  bf16_t* W2T  = (bf16_t*)(ws + 524288);
  bf16_t* W3T  = (bf16_t*)(ws + 655360);
  float*  out  = (float*)d_out;

  prep_kernel<<<dim3(96), dim3(256), 0, stream>>>(W1, W2, W3, Wp, W2T, W3T);
  k2_kernel<<<dim3(256), dim3(512), 0, stream>>>(ctx, cho, Wp, b1, b2, W2T, W3T,
                                                 b3, W4, b4, out);
}